// Round 10
// baseline (226.587 us; speedup 1.0000x reference)
//
#include <hip/hip_runtime.h>
#include <cmath>
#include <cfloat>
#include <climits>

constexpr int D    = 128;
constexpr int NT   = 512;          // 8 waves
constexpr int NW   = NT / 64;
constexpr int KMAX = 64;
constexpr int HOTPW = 6;           // hot slots per wave-range (6/32 ~= 19% of cand)
constexpr float EPS_ = 1e-10f;

// ---------- nontemporal float4 load ----------
typedef float vf4 __attribute__((ext_vector_type(4)));
__device__ __forceinline__ float4 ntload(const float4* p) {
  vf4 v = __builtin_nontemporal_load((const vf4*)p);
  return make_float4(v.x, v.y, v.z, v.w);
}

// ---------- DPP helpers (VALU-only cross-lane) ----------
template <int CTRL>
__device__ __forceinline__ float dpp_add(float x) {
  int y = __builtin_amdgcn_update_dpp(0, __float_as_int(x), CTRL, 0xf, 0xf, false);
  return x + __int_as_float(y);
}
template <int CTRL>
__device__ __forceinline__ float dpp_max(float x) {
  int y = __builtin_amdgcn_update_dpp(__float_as_int(x), __float_as_int(x),
                                      CTRL, 0xf, 0xf, false);
  return fmaxf(x, __int_as_float(y));
}
__device__ __forceinline__ float dpp_sum32(float x) {
  x = dpp_add<0x111>(x);
  x = dpp_add<0x112>(x);
  x = dpp_add<0x114>(x);
  x = dpp_add<0x118>(x);
  x = dpp_add<0x142>(x);
  return x;                        // valid in lanes 31 and 63
}
__device__ __forceinline__ float dpp_sum64(float x) {
  x = dpp_sum32(x);
  x = dpp_add<0x143>(x);
  return __int_as_float(__builtin_amdgcn_readlane(__float_as_int(x), 63));
}
__device__ __forceinline__ float dpp_max64(float x) {
  x = dpp_max<0x111>(x);
  x = dpp_max<0x112>(x);
  x = dpp_max<0x114>(x);
  x = dpp_max<0x118>(x);
  x = dpp_max<0x142>(x);
  x = dpp_max<0x143>(x);
  return __int_as_float(__builtin_amdgcn_readlane(__float_as_int(x), 63));
}

// ================= specialized fused kernel: N == NT*4 =================
// launch_bounds(512,8): VGPR<=64 -> 4 blocks/CU (even residency, 32 waves/CU).
__global__ __launch_bounds__(NT, 8) void fused2_kernel(
    const float* __restrict__ target, const float* __restrict__ cand,
    const float* __restrict__ Wq, const float* __restrict__ bq,
    const float* __restrict__ Wk, const float* __restrict__ u,
    const int* __restrict__ kptr, int* __restrict__ out, int N)
{
  extern __shared__ __align__(16) float sS[];   // N floats
  __shared__ __align__(16) float sTgt[D];
  __shared__ __align__(16) float sQ[D];
  __shared__ __align__(16) float sQt[D];
  __shared__ float redM[NW];
  __shared__ float cV[NW * KMAX];
  __shared__ int   cI[NW * KMAX];

  const int b    = blockIdx.x;
  const int tid  = threadIdx.x;
  const int lane = tid & 63;
  const int wave = tid >> 6;

  // ---- projections: qt = Wk^T (Wq t + bq); bk cancels in softmax ----
  if (tid < D) sTgt[tid] = target[(size_t)b * D + tid];
  __syncthreads();
  if (tid < D) {
    float acc = 0.f;
    const float* wrow = Wq + (size_t)tid * D;
    #pragma unroll 8
    for (int e = 0; e < D; ++e) acc += sTgt[e] * wrow[e];
    sQ[tid] = acc + bq[tid];
  }
  __syncthreads();
  if (tid < D) {
    float acc = 0.f;
    #pragma unroll 8
    for (int d = 0; d < D; ++d) acc += sQ[d] * Wk[(size_t)d * D + tid];
    sQt[tid] = acc;
  }
  __syncthreads();

  // ---- sweep: per-wave CONTIGUOUS 128KB sub-slab (sequential DRAM pages);
  //      first HOTPW slots of each range cached (L3), rest nontemporal ----
  const int p    = lane & 31;
  const int half = lane >> 5;
  const float4 qf = ((const float4*)sQt)[p];
  const float inv_scale = 1.0f / sqrtf((float)D);
  const float4* cb4 = (const float4*)(cand + (size_t)b * N * D);
  const bool writer = (p == 31);

  const int SLOTS    = N / 8;                    // 256 (8 rows per slot)
  const int PER_WAVE = SLOTS / NW;               // 32 contiguous slots per wave
  const int rot      = (b * 97) & (PER_WAVE - 1);
  const int base_slot = wave * PER_WAVE;

  for (int i = 0; i < PER_WAVE; ++i) {
    const int sir  = (i + rot) & (PER_WAVE - 1); // slot-in-range, sequential walk
    const int slot = base_slot + sir;
    const float4* pS = cb4 + (size_t)slot * 256 + lane;
    float4 a0, a1, a2, a3;
    if (sir < HOTPW) {                           // wave-uniform branch
      a0 = pS[0]; a1 = pS[64]; a2 = pS[128]; a3 = pS[192];
    } else {
      a0 = ntload(pS);       a1 = ntload(pS + 64);
      a2 = ntload(pS + 128); a3 = ntload(pS + 192);
    }
    float s0 = a0.x * qf.x + a0.y * qf.y + a0.z * qf.z + a0.w * qf.w;
    float s1 = a1.x * qf.x + a1.y * qf.y + a1.z * qf.z + a1.w * qf.w;
    float s2 = a2.x * qf.x + a2.y * qf.y + a2.z * qf.z + a2.w * qf.w;
    float s3 = a3.x * qf.x + a3.y * qf.y + a3.z * qf.z + a3.w * qf.w;
    s0 = dpp_sum32(s0); s1 = dpp_sum32(s1); s2 = dpp_sum32(s2); s3 = dpp_sum32(s3);
    if (writer) {
      const int n0 = slot * 8;
      sS[n0 + 0 + half] = s0 * inv_scale;
      sS[n0 + 2 + half] = s1 * inv_scale;
      sS[n0 + 4 + half] = s2 * inv_scale;
      sS[n0 + 6 + half] = s3 * inv_scale;
    }
  }
  __syncthreads();

  // ---- each thread owns 4 contiguous values ----
  const int iv = wave * 256 + lane * 4;
  float4 sv = *(const float4*)(sS + iv);
  float v0 = sv.x, v1 = sv.y, v2 = sv.z, v3 = sv.w;

  // row max
  float m = fmaxf(fmaxf(v0, v1), fmaxf(v2, v3));
  m = dpp_max64(m);
  if (lane == 0) redM[wave] = m;
  __syncthreads();
  m = redM[0];
  #pragma unroll
  for (int w = 1; w < NW; ++w) m = fmaxf(m, redM[w]);
  __syncthreads();

  // sum of exp
  float ssum = expf(v0 - m) + expf(v1 - m) + expf(v2 - m) + expf(v3 - m);
  ssum = dpp_sum64(ssum);
  if (lane == 0) redM[wave] = ssum;
  __syncthreads();
  float Z = redM[0];
  #pragma unroll
  for (int w = 1; w < NW; ++w) Z += redM[w];
  __syncthreads();

  // values: log(0.9*softmax + 0.1/N) + gumbel
  const float mixc = (float)(0.1 / (double)N);
  float4 uv = *(const float4*)(u + (size_t)b * N + iv);
  v0 = logf(0.9f * (expf(v0 - m) / Z) + mixc) + (-logf(-logf(uv.x + EPS_) + EPS_));
  v1 = logf(0.9f * (expf(v1 - m) / Z) + mixc) + (-logf(-logf(uv.y + EPS_) + EPS_));
  v2 = logf(0.9f * (expf(v2 - m) / Z) + mixc) + (-logf(-logf(uv.z + EPS_) + EPS_));
  v3 = logf(0.9f * (expf(v3 - m) / Z) + mixc) + (-logf(-logf(uv.w + EPS_) + EPS_));

  const int k = kptr[0];

  // ---- wave-local top-k (registers + shuffles only) ----
  for (int i = 0; i < k; ++i) {
    float bv = v0; int bj = 0;
    if (v1 > bv) { bv = v1; bj = 1; }
    if (v2 > bv) { bv = v2; bj = 2; }
    if (v3 > bv) { bv = v3; bj = 3; }
    int bidx = iv + bj;
    for (int s = 32; s; s >>= 1) {
      float ov = __shfl_xor(bv, s);
      int   oi = __shfl_xor(bidx, s);
      if (ov > bv || (ov == bv && oi < bidx)) { bv = ov; bidx = oi; }
    }
    if (lane == ((bidx & 255) >> 2)) {
      int off = bidx & 3;
      if (off == 0) v0 = -FLT_MAX;
      if (off == 1) v1 = -FLT_MAX;
      if (off == 2) v2 = -FLT_MAX;
      if (off == 3) v3 = -FLT_MAX;
    }
    if (lane == 0) { cV[wave * KMAX + i] = bv; cI[wave * KMAX + i] = bidx; }
  }
  __syncthreads();

  // ---- merge NW*k candidates on wave 0 ----
  if (wave == 0) {
    const int tot = NW * k;
    float mv[8]; int mi[8];
    #pragma unroll
    for (int t = 0; t < 8; ++t) {
      int c = lane + 64 * t;
      if (c < tot) {
        int w = c / k, i = c % k;
        mv[t] = cV[w * KMAX + i]; mi[t] = cI[w * KMAX + i];
      } else { mv[t] = -FLT_MAX; mi[t] = INT_MAX; }
    }
    for (int i = 0; i < k; ++i) {
      float bv = mv[0]; int bidx = mi[0];
      #pragma unroll
      for (int t = 1; t < 8; ++t)
        if (mv[t] > bv || (mv[t] == bv && mi[t] < bidx)) { bv = mv[t]; bidx = mi[t]; }
      for (int s = 32; s; s >>= 1) {
        float ov = __shfl_xor(bv, s);
        int   oi = __shfl_xor(bidx, s);
        if (ov > bv || (ov == bv && oi < bidx)) { bv = ov; bidx = oi; }
      }
      #pragma unroll
      for (int t = 0; t < 8; ++t) if (mi[t] == bidx) mv[t] = -FLT_MAX;
      if (lane == 0) out[(size_t)b * k + i] = bidx;
    }
  }
}

// =============== fallback: generic fused kernel (R1 structure) ===============
constexpr int NTF = 512;
constexpr int NWF = NTF / 64;
__global__ __launch_bounds__(NTF, 8) void fused_kernel(
    const float* __restrict__ target, const float* __restrict__ cand,
    const float* __restrict__ Wq, const float* __restrict__ bq,
    const float* __restrict__ Wk, const float* __restrict__ u,
    const int* __restrict__ kptr, int* __restrict__ out, int N)
{
  extern __shared__ float sS[];
  __shared__ float sTgt[D];
  __shared__ float sQ[D];
  __shared__ float sQt[D];
  __shared__ float redV[NWF];
  __shared__ int   redI[NWF];

  const int b = blockIdx.x, tid = threadIdx.x;
  const int lane = tid & 63, wave = tid >> 6;

  if (tid < D) sTgt[tid] = target[(size_t)b * D + tid];
  __syncthreads();
  if (tid < D) {
    float acc = 0.f;
    const float* wrow = Wq + (size_t)tid * D;
    #pragma unroll 8
    for (int e = 0; e < D; ++e) acc += sTgt[e] * wrow[e];
    sQ[tid] = acc + bq[tid];
  }
  __syncthreads();
  if (tid < D) {
    float acc = 0.f;
    #pragma unroll 8
    for (int d = 0; d < D; ++d) acc += sQ[d] * Wk[(size_t)d * D + tid];
    sQt[tid] = acc;
  }
  __syncthreads();

  const int grp = lane >> 4, gl = lane & 15;
  float q0 = sQt[gl*8+0], q1 = sQt[gl*8+1], q2 = sQt[gl*8+2], q3 = sQt[gl*8+3];
  float q4 = sQt[gl*8+4], q5 = sQt[gl*8+5], q6 = sQt[gl*8+6], q7 = sQt[gl*8+7];
  const float scale = sqrtf((float)D);
  const int rstride = NWF * 4;
  int n = wave * 4 + grp;
  for (; n + rstride < N; n += 2 * rstride) {
    const float4* r0 = (const float4*)(cand + ((size_t)b * N + n) * D);
    const float4* r1 = (const float4*)(cand + ((size_t)b * N + n + rstride) * D);
    float4 a0 = r0[gl*2+0], a1 = r0[gl*2+1], c0 = r1[gl*2+0], c1 = r1[gl*2+1];
    float p0 = a0.x*q0 + a0.y*q1 + a0.z*q2 + a0.w*q3 + a1.x*q4 + a1.y*q5 + a1.z*q6 + a1.w*q7;
    float p1 = c0.x*q0 + c0.y*q1 + c0.z*q2 + c0.w*q3 + c1.x*q4 + c1.y*q5 + c1.z*q6 + c1.w*q7;
    p0 += __shfl_xor(p0,1); p1 += __shfl_xor(p1,1);
    p0 += __shfl_xor(p0,2); p1 += __shfl_xor(p1,2);
    p0 += __shfl_xor(p0,4); p1 += __shfl_xor(p1,4);
    p0 += __shfl_xor(p0,8); p1 += __shfl_xor(p1,8);
    if (gl == 0) { sS[n] = p0 / scale; sS[n + rstride] = p1 / scale; }
  }
  if (n < N) {
    const float4* r0 = (const float4*)(cand + ((size_t)b * N + n) * D);
    float4 a0 = r0[gl*2+0], a1 = r0[gl*2+1];
    float p0 = a0.x*q0 + a0.y*q1 + a0.z*q2 + a0.w*q3 + a1.x*q4 + a1.y*q5 + a1.z*q6 + a1.w*q7;
    p0 += __shfl_xor(p0,1); p0 += __shfl_xor(p0,2); p0 += __shfl_xor(p0,4); p0 += __shfl_xor(p0,8);
    if (gl == 0) sS[n] = p0 / scale;
  }
  __syncthreads();

  float m = -FLT_MAX;
  for (int i = tid; i < N; i += NTF) m = fmaxf(m, sS[i]);
  for (int s = 32; s; s >>= 1) m = fmaxf(m, __shfl_xor(m, s));
  if (lane == 0) redV[wave] = m;
  __syncthreads();
  m = redV[0];
  #pragma unroll
  for (int w = 1; w < NWF; ++w) m = fmaxf(m, redV[w]);
  __syncthreads();

  float ssum = 0.f;
  for (int i = tid; i < N; i += NTF) ssum += expf(sS[i] - m);
  for (int s = 32; s; s >>= 1) ssum += __shfl_xor(ssum, s);
  if (lane == 0) redV[wave] = ssum;
  __syncthreads();
  float Z = redV[0];
  #pragma unroll
  for (int w = 1; w < NWF; ++w) Z += redV[w];
  __syncthreads();

  const float mixc = (float)(0.1 / (double)N);
  for (int i = tid; i < N; i += NTF) {
    float pmix = 0.9f * (expf(sS[i] - m) / Z) + mixc;
    float uvs = u[(size_t)b * N + i];
    float g = -logf(-logf(uvs + EPS_) + EPS_);
    sS[i] = logf(pmix) + g;
  }
  __syncthreads();

  const int k = kptr[0];
  for (int i = 0; i < k; ++i) {
    float bv = -FLT_MAX; int bi = N;
    for (int j = tid; j < N; j += NTF) {
      float vv = sS[j];
      if (vv > bv || (vv == bv && j < bi)) { bv = vv; bi = j; }
    }
    for (int s = 32; s; s >>= 1) {
      float ov = __shfl_xor(bv, s); int oi = __shfl_xor(bi, s);
      if (ov > bv || (ov == bv && oi < bi)) { bv = ov; bi = oi; }
    }
    if (lane == 0) { redV[wave] = bv; redI[wave] = bi; }
    __syncthreads();
    if (tid == 0) {
      float fv = redV[0]; int fi = redI[0];
      #pragma unroll
      for (int w = 1; w < NWF; ++w)
        if (redV[w] > fv || (redV[w] == fv && redI[w] < fi)) { fv = redV[w]; fi = redI[w]; }
      out[(size_t)b * k + i] = fi;
      sS[fi] = -FLT_MAX;
    }
    __syncthreads();
  }
}

extern "C" void kernel_launch(void* const* d_in, const int* in_sizes, int n_in,
                              void* d_out, int out_size, void* d_ws, size_t ws_size,
                              hipStream_t stream) {
  const float* target = (const float*)d_in[0];
  const float* cand   = (const float*)d_in[1];
  const float* Wq     = (const float*)d_in[2];
  const float* bq     = (const float*)d_in[3];
  const float* Wk     = (const float*)d_in[4];
  const float* bk     = (const float*)d_in[5];  // cancels in softmax
  const float* u      = (const float*)d_in[6];
  const int*   kptr   = (const int*)d_in[7];
  (void)bk; (void)n_in; (void)d_ws; (void)ws_size;

  const int B = in_sizes[0] / D;
  const int N = in_sizes[1] / (B * D);
  const int k = out_size / B;

  if (N == NT * 4 && (N % 64) == 0 && k <= KMAX) {
    fused2_kernel<<<B, NT, N * sizeof(float), stream>>>(
        target, cand, Wq, bq, Wk, u, kptr, (int*)d_out, N);
  } else {
    fused_kernel<<<B, NTF, N * sizeof(float), stream>>>(
        target, cand, Wq, bq, Wk, u, kptr, (int*)d_out, N);
  }
}

// Round 11
// 217.273 us; speedup vs baseline: 1.0429x; 1.0429x over previous
//
#include <hip/hip_runtime.h>
#include <cmath>
#include <cfloat>
#include <climits>

constexpr int D    = 128;
constexpr int NT   = 512;          // 8 waves
constexpr int NW   = NT / 64;
constexpr int KMAX = 64;
constexpr int HOTSLOTS = 48;       // 48/256 slots (~19% of cand) kept L3-resident
constexpr float EPS_ = 1e-10f;

// ---------- nontemporal float4 load ----------
typedef float vf4 __attribute__((ext_vector_type(4)));
__device__ __forceinline__ float4 ntload(const float4* p) {
  vf4 v = __builtin_nontemporal_load((const vf4*)p);
  return make_float4(v.x, v.y, v.z, v.w);
}

// ---------- DPP helpers (VALU-only cross-lane) ----------
template <int CTRL>
__device__ __forceinline__ float dpp_add(float x) {
  int y = __builtin_amdgcn_update_dpp(0, __float_as_int(x), CTRL, 0xf, 0xf, false);
  return x + __int_as_float(y);
}
template <int CTRL>
__device__ __forceinline__ float dpp_max(float x) {
  int y = __builtin_amdgcn_update_dpp(__float_as_int(x), __float_as_int(x),
                                      CTRL, 0xf, 0xf, false);
  return fmaxf(x, __int_as_float(y));
}
__device__ __forceinline__ float dpp_sum32(float x) {
  x = dpp_add<0x111>(x);
  x = dpp_add<0x112>(x);
  x = dpp_add<0x114>(x);
  x = dpp_add<0x118>(x);
  x = dpp_add<0x142>(x);
  return x;                        // valid in lanes 31 and 63
}
__device__ __forceinline__ float dpp_sum64(float x) {
  x = dpp_sum32(x);
  x = dpp_add<0x143>(x);
  return __int_as_float(__builtin_amdgcn_readlane(__float_as_int(x), 63));
}
__device__ __forceinline__ float dpp_max64(float x) {
  x = dpp_max<0x111>(x);
  x = dpp_max<0x112>(x);
  x = dpp_max<0x114>(x);
  x = dpp_max<0x118>(x);
  x = dpp_max<0x142>(x);
  x = dpp_max<0x143>(x);
  return __int_as_float(__builtin_amdgcn_readlane(__float_as_int(x), 63));
}

// ================= specialized fused kernel: N == NT*4 =================
// launch_bounds(512,8): VGPR<=64 -> 4 blocks/CU (even residency, 32 waves/CU).
__global__ __launch_bounds__(NT, 8) void fused2_kernel(
    const float* __restrict__ target, const float* __restrict__ cand,
    const float* __restrict__ Wq, const float* __restrict__ bq,
    const float* __restrict__ Wk, const float* __restrict__ u,
    const int* __restrict__ kptr, int* __restrict__ out, int N)
{
  extern __shared__ __align__(16) float sS[];   // N floats
  __shared__ __align__(16) float sTgt[D];
  __shared__ __align__(16) float sQ[D];
  __shared__ __align__(16) float sQt[D];
  __shared__ float redM[NW];
  __shared__ float cV[NW * KMAX];
  __shared__ int   cI[NW * KMAX];

  const int b    = blockIdx.x;
  const int tid  = threadIdx.x;
  const int lane = tid & 63;
  const int wave = tid >> 6;

  // ---- projections: qt = Wk^T (Wq t + bq); bk cancels in softmax ----
  if (tid < D) sTgt[tid] = target[(size_t)b * D + tid];
  __syncthreads();
  if (tid < D) {
    float acc = 0.f;
    const float* wrow = Wq + (size_t)tid * D;
    #pragma unroll 8
    for (int e = 0; e < D; ++e) acc += sTgt[e] * wrow[e];
    sQ[tid] = acc + bq[tid];
  }
  __syncthreads();
  if (tid < D) {
    float acc = 0.f;
    #pragma unroll 8
    for (int d = 0; d < D; ++d) acc += sQ[d] * Wk[(size_t)d * D + tid];
    sQt[tid] = acc;
  }
  __syncthreads();

  // ---- sweep: contiguous 1KB loads; hot slots cached (L3-resident across
  //      replays), cold slots nontemporal so they can't evict the hot set ----
  const int p    = lane & 31;
  const int half = lane >> 5;
  const float4 qf = ((const float4*)sQt)[p];
  const float inv_scale = 1.0f / sqrtf((float)D);
  const float4* cb4 = (const float4*)(cand + (size_t)b * N * D);
  const bool writer = (p == 31);

  const int SLOTS = N / 8;                  // 256 (8 rows per slot)
  const int ITERS = SLOTS / NW;             // 32
  const int rot   = (b * 97) & (SLOTS - 1); // per-block phase rotation

  for (int i = 0; i < ITERS; ++i) {
    const int slot = (wave + NW * i + rot) & (SLOTS - 1);
    const float4* pS = cb4 + (size_t)slot * 256 + lane;
    float4 a0, a1, a2, a3;
    if (slot < HOTSLOTS) {                  // wave-uniform branch
      a0 = pS[0]; a1 = pS[64]; a2 = pS[128]; a3 = pS[192];
    } else {
      a0 = ntload(pS);       a1 = ntload(pS + 64);
      a2 = ntload(pS + 128); a3 = ntload(pS + 192);
    }
    float s0 = a0.x * qf.x + a0.y * qf.y + a0.z * qf.z + a0.w * qf.w;
    float s1 = a1.x * qf.x + a1.y * qf.y + a1.z * qf.z + a1.w * qf.w;
    float s2 = a2.x * qf.x + a2.y * qf.y + a2.z * qf.z + a2.w * qf.w;
    float s3 = a3.x * qf.x + a3.y * qf.y + a3.z * qf.z + a3.w * qf.w;
    s0 = dpp_sum32(s0); s1 = dpp_sum32(s1); s2 = dpp_sum32(s2); s3 = dpp_sum32(s3);
    if (writer) {
      const int n0 = slot * 8;
      sS[n0 + 0 + half] = s0 * inv_scale;
      sS[n0 + 2 + half] = s1 * inv_scale;
      sS[n0 + 4 + half] = s2 * inv_scale;
      sS[n0 + 6 + half] = s3 * inv_scale;
    }
  }
  __syncthreads();

  // ---- each thread owns 4 contiguous values ----
  const int iv = wave * 256 + lane * 4;
  float4 sv = *(const float4*)(sS + iv);
  float v0 = sv.x, v1 = sv.y, v2 = sv.z, v3 = sv.w;

  // row max
  float m = fmaxf(fmaxf(v0, v1), fmaxf(v2, v3));
  m = dpp_max64(m);
  if (lane == 0) redM[wave] = m;
  __syncthreads();
  m = redM[0];
  #pragma unroll
  for (int w = 1; w < NW; ++w) m = fmaxf(m, redM[w]);
  __syncthreads();

  // sum of exp
  float ssum = expf(v0 - m) + expf(v1 - m) + expf(v2 - m) + expf(v3 - m);
  ssum = dpp_sum64(ssum);
  if (lane == 0) redM[wave] = ssum;
  __syncthreads();
  float Z = redM[0];
  #pragma unroll
  for (int w = 1; w < NW; ++w) Z += redM[w];
  __syncthreads();

  // values: log(0.9*softmax + 0.1/N) + gumbel
  const float mixc = (float)(0.1 / (double)N);
  float4 uv = *(const float4*)(u + (size_t)b * N + iv);
  v0 = logf(0.9f * (expf(v0 - m) / Z) + mixc) + (-logf(-logf(uv.x + EPS_) + EPS_));
  v1 = logf(0.9f * (expf(v1 - m) / Z) + mixc) + (-logf(-logf(uv.y + EPS_) + EPS_));
  v2 = logf(0.9f * (expf(v2 - m) / Z) + mixc) + (-logf(-logf(uv.z + EPS_) + EPS_));
  v3 = logf(0.9f * (expf(v3 - m) / Z) + mixc) + (-logf(-logf(uv.w + EPS_) + EPS_));

  const int k = kptr[0];

  // ---- wave-local top-k (registers + shuffles only) ----
  for (int i = 0; i < k; ++i) {
    float bv = v0; int bj = 0;
    if (v1 > bv) { bv = v1; bj = 1; }
    if (v2 > bv) { bv = v2; bj = 2; }
    if (v3 > bv) { bv = v3; bj = 3; }
    int bidx = iv + bj;
    for (int s = 32; s; s >>= 1) {
      float ov = __shfl_xor(bv, s);
      int   oi = __shfl_xor(bidx, s);
      if (ov > bv || (ov == bv && oi < bidx)) { bv = ov; bidx = oi; }
    }
    if (lane == ((bidx & 255) >> 2)) {
      int off = bidx & 3;
      if (off == 0) v0 = -FLT_MAX;
      if (off == 1) v1 = -FLT_MAX;
      if (off == 2) v2 = -FLT_MAX;
      if (off == 3) v3 = -FLT_MAX;
    }
    if (lane == 0) { cV[wave * KMAX + i] = bv; cI[wave * KMAX + i] = bidx; }
  }
  __syncthreads();

  // ---- merge NW*k candidates on wave 0 ----
  if (wave == 0) {
    const int tot = NW * k;
    float mv[8]; int mi[8];
    #pragma unroll
    for (int t = 0; t < 8; ++t) {
      int c = lane + 64 * t;
      if (c < tot) {
        int w = c / k, i = c % k;
        mv[t] = cV[w * KMAX + i]; mi[t] = cI[w * KMAX + i];
      } else { mv[t] = -FLT_MAX; mi[t] = INT_MAX; }
    }
    for (int i = 0; i < k; ++i) {
      float bv = mv[0]; int bidx = mi[0];
      #pragma unroll
      for (int t = 1; t < 8; ++t)
        if (mv[t] > bv || (mv[t] == bv && mi[t] < bidx)) { bv = mv[t]; bidx = mi[t]; }
      for (int s = 32; s; s >>= 1) {
        float ov = __shfl_xor(bv, s);
        int   oi = __shfl_xor(bidx, s);
        if (ov > bv || (ov == bv && oi < bidx)) { bv = ov; bidx = oi; }
      }
      #pragma unroll
      for (int t = 0; t < 8; ++t) if (mi[t] == bidx) mv[t] = -FLT_MAX;
      if (lane == 0) out[(size_t)b * k + i] = bidx;
    }
  }
}

// =============== fallback: generic fused kernel (R1 structure) ===============
constexpr int NTF = 512;
constexpr int NWF = NTF / 64;
__global__ __launch_bounds__(NTF, 8) void fused_kernel(
    const float* __restrict__ target, const float* __restrict__ cand,
    const float* __restrict__ Wq, const float* __restrict__ bq,
    const float* __restrict__ Wk, const float* __restrict__ u,
    const int* __restrict__ kptr, int* __restrict__ out, int N)
{
  extern __shared__ float sS[];
  __shared__ float sTgt[D];
  __shared__ float sQ[D];
  __shared__ float sQt[D];
  __shared__ float redV[NWF];
  __shared__ int   redI[NWF];

  const int b = blockIdx.x, tid = threadIdx.x;
  const int lane = tid & 63, wave = tid >> 6;

  if (tid < D) sTgt[tid] = target[(size_t)b * D + tid];
  __syncthreads();
  if (tid < D) {
    float acc = 0.f;
    const float* wrow = Wq + (size_t)tid * D;
    #pragma unroll 8
    for (int e = 0; e < D; ++e) acc += sTgt[e] * wrow[e];
    sQ[tid] = acc + bq[tid];
  }
  __syncthreads();
  if (tid < D) {
    float acc = 0.f;
    #pragma unroll 8
    for (int d = 0; d < D; ++d) acc += sQ[d] * Wk[(size_t)d * D + tid];
    sQt[tid] = acc;
  }
  __syncthreads();

  const int grp = lane >> 4, gl = lane & 15;
  float q0 = sQt[gl*8+0], q1 = sQt[gl*8+1], q2 = sQt[gl*8+2], q3 = sQt[gl*8+3];
  float q4 = sQt[gl*8+4], q5 = sQt[gl*8+5], q6 = sQt[gl*8+6], q7 = sQt[gl*8+7];
  const float scale = sqrtf((float)D);
  const int rstride = NWF * 4;
  int n = wave * 4 + grp;
  for (; n + rstride < N; n += 2 * rstride) {
    const float4* r0 = (const float4*)(cand + ((size_t)b * N + n) * D);
    const float4* r1 = (const float4*)(cand + ((size_t)b * N + n + rstride) * D);
    float4 a0 = r0[gl*2+0], a1 = r0[gl*2+1], c0 = r1[gl*2+0], c1 = r1[gl*2+1];
    float p0 = a0.x*q0 + a0.y*q1 + a0.z*q2 + a0.w*q3 + a1.x*q4 + a1.y*q5 + a1.z*q6 + a1.w*q7;
    float p1 = c0.x*q0 + c0.y*q1 + c0.z*q2 + c0.w*q3 + c1.x*q4 + c1.y*q5 + c1.z*q6 + c1.w*q7;
    p0 += __shfl_xor(p0,1); p1 += __shfl_xor(p1,1);
    p0 += __shfl_xor(p0,2); p1 += __shfl_xor(p1,2);
    p0 += __shfl_xor(p0,4); p1 += __shfl_xor(p1,4);
    p0 += __shfl_xor(p0,8); p1 += __shfl_xor(p1,8);
    if (gl == 0) { sS[n] = p0 / scale; sS[n + rstride] = p1 / scale; }
  }
  if (n < N) {
    const float4* r0 = (const float4*)(cand + ((size_t)b * N + n) * D);
    float4 a0 = r0[gl*2+0], a1 = r0[gl*2+1];
    float p0 = a0.x*q0 + a0.y*q1 + a0.z*q2 + a0.w*q3 + a1.x*q4 + a1.y*q5 + a1.z*q6 + a1.w*q7;
    p0 += __shfl_xor(p0,1); p0 += __shfl_xor(p0,2); p0 += __shfl_xor(p0,4); p0 += __shfl_xor(p0,8);
    if (gl == 0) sS[n] = p0 / scale;
  }
  __syncthreads();

  float m = -FLT_MAX;
  for (int i = tid; i < N; i += NTF) m = fmaxf(m, sS[i]);
  for (int s = 32; s; s >>= 1) m = fmaxf(m, __shfl_xor(m, s));
  if (lane == 0) redV[wave] = m;
  __syncthreads();
  m = redV[0];
  #pragma unroll
  for (int w = 1; w < NWF; ++w) m = fmaxf(m, redV[w]);
  __syncthreads();

  float ssum = 0.f;
  for (int i = tid; i < N; i += NTF) ssum += expf(sS[i] - m);
  for (int s = 32; s; s >>= 1) ssum += __shfl_xor(ssum, s);
  if (lane == 0) redV[wave] = ssum;
  __syncthreads();
  float Z = redV[0];
  #pragma unroll
  for (int w = 1; w < NWF; ++w) Z += redV[w];
  __syncthreads();

  const float mixc = (float)(0.1 / (double)N);
  for (int i = tid; i < N; i += NTF) {
    float pmix = 0.9f * (expf(sS[i] - m) / Z) + mixc;
    float uvs = u[(size_t)b * N + i];
    float g = -logf(-logf(uvs + EPS_) + EPS_);
    sS[i] = logf(pmix) + g;
  }
  __syncthreads();

  const int k = kptr[0];
  for (int i = 0; i < k; ++i) {
    float bv = -FLT_MAX; int bi = N;
    for (int j = tid; j < N; j += NTF) {
      float vv = sS[j];
      if (vv > bv || (vv == bv && j < bi)) { bv = vv; bi = j; }
    }
    for (int s = 32; s; s >>= 1) {
      float ov = __shfl_xor(bv, s); int oi = __shfl_xor(bi, s);
      if (ov > bv || (ov == bv && oi < bi)) { bv = ov; bi = oi; }
    }
    if (lane == 0) { redV[wave] = bv; redI[wave] = bi; }
    __syncthreads();
    if (tid == 0) {
      float fv = redV[0]; int fi = redI[0];
      #pragma unroll
      for (int w = 1; w < NWF; ++w)
        if (redV[w] > fv || (redV[w] == fv && redI[w] < fi)) { fv = redV[w]; fi = redI[w]; }
      out[(size_t)b * k + i] = fi;
      sS[fi] = -FLT_MAX;
    }
    __syncthreads();
  }
}

extern "C" void kernel_launch(void* const* d_in, const int* in_sizes, int n_in,
                              void* d_out, int out_size, void* d_ws, size_t ws_size,
                              hipStream_t stream) {
  const float* target = (const float*)d_in[0];
  const float* cand   = (const float*)d_in[1];
  const float* Wq     = (const float*)d_in[2];
  const float* bq     = (const float*)d_in[3];
  const float* Wk     = (const float*)d_in[4];
  const float* bk     = (const float*)d_in[5];  // cancels in softmax
  const float* u      = (const float*)d_in[6];
  const int*   kptr   = (const int*)d_in[7];
  (void)bk; (void)n_in; (void)d_ws; (void)ws_size;

  const int B = in_sizes[0] / D;
  const int N = in_sizes[1] / (B * D);
  const int k = out_size / B;

  if (N == NT * 4 && (N % 64) == 0 && k <= KMAX) {
    fused2_kernel<<<B, NT, N * sizeof(float), stream>>>(
        target, cand, Wq, bq, Wk, u, kptr, (int*)d_out, N);
  } else {
    fused_kernel<<<B, NTF, N * sizeof(float), stream>>>(
        target, cand, Wq, bq, Wk, u, kptr, (int*)d_out, N);
  }
}